// Round 9
// baseline (173.925 us; speedup 1.0000x reference)
//
#include <hip/hip_runtime.h>
#include <hip/hip_bf16.h>

// Round 9 = r7 (best: 81us) minus braid, plus three LDS-pipe cuts:
//  1. PV b64->b128: V^T stored phys-interleaved phys(k)=g*16+(k>>4)*4+(k&3);
//     prefetch key-remap (K0=32(w&1)+4(w>>1); keys {K0..+3, K0+16..+19}) makes
//     each thread's 8 keys one contiguous granule -> store stays r7's proven
//     XOR-swizzled single b128. One b128 read feeds TWO chunk fragments.
//  2. Em/LDS mask -> per-chunk global dwordx4 (L1-hot, quad-broadcast) with
//     p = exp2(fma(m, LOG2E, st)), C-init = 0. Moves 48cy/tile/wave off the
//     saturated LDS pipe onto the idle VMEM pipe.
//  3. LDS 45->36.9KB + launch_bounds(512,6): 3-4 blocks/CU co-resident for
//     cross-block overlap of staging vs compute (m114 wave-level TLP).

typedef __attribute__((ext_vector_type(8))) short bf16x8;
typedef __attribute__((ext_vector_type(4))) short bf16x4;
typedef __attribute__((ext_vector_type(4))) float f32x4;

#define B_ 2
#define S_ 2048
#define H_ 16
#define D_ 64
#define BQ 128
#define BK 64
#define NT (S_ / BK)
#define LDK 72                 // padded LDS row (144 B)
#define ROWSZ (H_ * D_)        // 1024 floats between s rows

#define LOG2E  1.44269504088896340736f
#define SCALE2 (0.125f * LOG2E)

__device__ __forceinline__ unsigned pack2(float a, float b) {
    union { __hip_bfloat162 h; unsigned u; } x;
    x.h = __float22bfloat162_rn(make_float2(a, b));   // v_cvt_pk_bf16_f32
    return x.u;
}

__device__ __forceinline__ float fexp2(float x) {
#if __has_builtin(__builtin_amdgcn_exp2f)
    return __builtin_amdgcn_exp2f(x);
#else
    return __expf(x * 0.69314718055994531f);
#endif
}

__device__ __forceinline__ f32x4 mfma16(bf16x4 a, bf16x4 b, f32x4 c) {
#if __has_builtin(__builtin_amdgcn_mfma_f32_16x16x16bf16_1k)
    return __builtin_amdgcn_mfma_f32_16x16x16bf16_1k(a, b, c, 0, 0, 0);
#else
    bf16x8 a8 = {a[0], a[1], a[2], a[3], 0, 0, 0, 0};
    bf16x8 b8 = {b[0], b[1], b[2], b[3], 0, 0, 0, 0};
    return __builtin_amdgcn_mfma_f32_16x16x32_bf16(a8, b8, c, 0, 0, 0);
#endif
}

__global__ __launch_bounds__(512, 6)
void fattn_kernel(const float* __restrict__ qg,
                  const float* __restrict__ kg,
                  const float* __restrict__ vg,
                  const float* __restrict__ maskg,
                  float* __restrict__ outg)
{
    __shared__ __attribute__((aligned(16))) ushort Ks[2][BK * LDK];  // row=key, col=d
    __shared__ __attribute__((aligned(16))) ushort Vt[2][D_ * LDK];  // row=d, interleaved+swizzled

    const int qt = blockIdx.x, h = blockIdx.y, b = blockIdx.z;
    const int tid = threadIdx.x;
    const int w = tid >> 6, lane = tid & 63, g = lane >> 4, l15 = lane & 15;
    const int h3 = l15 >> 3;

    // ---- Q fragment (B-operand, x32), scale folded in ----
    const int qrow = qt * BQ + w * 16 + l15;
    const float* qp = qg + (size_t)(b * S_ + qrow) * ROWSZ + h * D_;
    bf16x8 qf[2];
#pragma unroll
    for (int half = 0; half < 2; ++half) {
        float4 f0 = *(const float4*)(qp + half * 32 + g * 8);
        float4 f1 = *(const float4*)(qp + half * 32 + g * 8 + 4);
        union { bf16x8 v; uint4 u; } x;
        x.u = make_uint4(pack2(f0.x * SCALE2, f0.y * SCALE2),
                         pack2(f0.z * SCALE2, f0.w * SCALE2),
                         pack2(f1.x * SCALE2, f1.y * SCALE2),
                         pack2(f1.z * SCALE2, f1.w * SCALE2));
        qf[half] = x.v;
    }

    // staging maps
    const int skey16 = tid >> 4;        // K rows (tid>>4), +32 second pass
    const int sd4    = (tid & 15) * 4;  // K d-offset (float4)
    const int svd    = lane;            // V: d = lane
    const int K0     = 32 * (w & 1) + 4 * (w >> 1);   // V key-remap base
    const int vphys  = (w ^ ((lane >> 3) & 7)) * 8;   // XOR-swizzled granule

    const size_t kvbase = (size_t)b * S_ * ROWSZ + h * D_;
    const float* maskb = maskg + (size_t)b * S_;

    float4 kpre0, kpre1;
    float  vpre[8];
    auto prefetch = [&](int kt) {
        const float* kb = kg + kvbase + (size_t)kt * BK * ROWSZ;
        kpre0 = *(const float4*)(kb + (size_t)skey16 * ROWSZ + sd4);
        kpre1 = *(const float4*)(kb + (size_t)(skey16 + 32) * ROWSZ + sd4);
        const float* vb = vg + kvbase + (size_t)kt * BK * ROWSZ + svd;
#pragma unroll
        for (int p = 0; p < 4; ++p) {
            vpre[p]     = vb[(size_t)(K0 + p) * ROWSZ];
            vpre[4 + p] = vb[(size_t)(K0 + 16 + p) * ROWSZ];
        }
    };
    auto stage = [&](int buf) {
        *(uint2*)&Ks[buf][skey16 * LDK + sd4] =
            make_uint2(pack2(kpre0.x, kpre0.y), pack2(kpre0.z, kpre0.w));
        *(uint2*)&Ks[buf][(skey16 + 32) * LDK + sd4] =
            make_uint2(pack2(kpre1.x, kpre1.y), pack2(kpre1.z, kpre1.w));
        *(uint4*)&Vt[buf][svd * LDK + vphys] =
            make_uint4(pack2(vpre[0], vpre[1]), pack2(vpre[2], vpre[3]),
                       pack2(vpre[4], vpre[5]), pack2(vpre[6], vpre[7]));
    };

    float l_r = 0.0f;                   // per-lane (q=l15) partial denominator
    f32x4 o_acc[4];
#pragma unroll
    for (int t = 0; t < 4; ++t) o_acc[t] = (f32x4){0.f, 0.f, 0.f, 0.f};

    prefetch(0);
    stage(0);
    __syncthreads();

    const int koff = l15 * LDK + g * 8;

    for (int kt = 0; kt < NT; ++kt) {
        const int cur = kt & 1;
        if (kt + 1 < NT) prefetch(kt + 1);   // loads in flight across compute

        // ---- St = K Q^T (C=0) : St[key=t*16+g*4+r][q=l15] ----
        const ushort* ks = Ks[cur];
        float sv[4][4];
#pragma unroll
        for (int t = 0; t < 4; ++t) {
            f32x4 acc = (f32x4){0.f, 0.f, 0.f, 0.f};
            bf16x8 kf0 = *(const bf16x8*)&ks[t * 16 * LDK + koff];
            bf16x8 kf1 = *(const bf16x8*)&ks[t * 16 * LDK + koff + 32];
            acc = __builtin_amdgcn_mfma_f32_16x16x32_bf16(kf0, qf[0], acc, 0, 0, 0);
            acc = __builtin_amdgcn_mfma_f32_16x16x32_bf16(kf1, qf[1], acc, 0, 0, 0);
            sv[t][0] = acc[0]; sv[t][1] = acc[1]; sv[t][2] = acc[2]; sv[t][3] = acc[3];
        }

        // ---- fixed-base softmax with mask from global (L1-hot broadcast) ----
        float rs = 0.f;
        bf16x4 pf[4];
#pragma unroll
        for (int t = 0; t < 4; ++t) {
            const f32x4 mk = *(const f32x4*)(maskb + kt * BK + t * 16 + g * 4);
            float p0 = fexp2(fmaf(mk[0], LOG2E, sv[t][0]));
            float p1 = fexp2(fmaf(mk[1], LOG2E, sv[t][1]));
            float p2 = fexp2(fmaf(mk[2], LOG2E, sv[t][2]));
            float p3 = fexp2(fmaf(mk[3], LOG2E, sv[t][3]));
            rs += (p0 + p1) + (p2 + p3);
            union { bf16x4 v; uint2 u; } x;
            x.u = make_uint2(pack2(p0, p1), pack2(p2, p3));
            pf[t] = x.v;
        }
        l_r += rs;

        // ---- O^T += V^T P^T : 8 b128 reads, each feeds 2 chunk fragments ----
        const ushort* vt = Vt[cur];
#pragma unroll
        for (int t2 = 0; t2 < 4; ++t2) {
            const int e = (2 * t2 + h3) & 7;          // (d>>3)&7 for d=t2*16+l15
            const int row = (t2 * 16 + l15) * LDK;
#pragma unroll
            for (int cc = 0; cc < 2; ++cc) {
                const int Gs = (2 * g + cc) ^ e;
                bf16x8 vv = *(const bf16x8*)&vt[row + Gs * 8];
                bf16x4 vlo = {vv[0], vv[1], vv[2], vv[3]};   // chunk 2cc
                bf16x4 vhi = {vv[4], vv[5], vv[6], vv[7]};   // chunk 2cc+1
                o_acc[t2] = mfma16(vlo, pf[2 * cc],     o_acc[t2]);
                o_acc[t2] = mfma16(vhi, pf[2 * cc + 1], o_acc[t2]);
            }
        }

        if (kt + 1 < NT) stage(cur ^ 1);    // vmcnt drain lands post-compute
        __syncthreads();                    // single barrier per tile
    }

    // ---- epilogue: reduce l across quads, normalize, store fp32 ----
    l_r += __shfl_xor(l_r, 16);
    l_r += __shfl_xor(l_r, 32);
    const float inv = 1.0f / l_r;
    float* op = outg + (size_t)(b * S_ + qrow) * ROWSZ + h * D_;
#pragma unroll
    for (int t2 = 0; t2 < 4; ++t2)
#pragma unroll
        for (int r = 0; r < 4; ++r)
            op[t2 * 16 + g * 4 + r] = o_acc[t2][r] * inv;
}

extern "C" void kernel_launch(void* const* d_in, const int* in_sizes, int n_in,
                              void* d_out, int out_size, void* d_ws, size_t ws_size,
                              hipStream_t stream) {
    dim3 grid(S_ / BQ, H_, B_);   // (16,16,2) = 512 blocks
    fattn_kernel<<<grid, dim3(512), 0, stream>>>(
        (const float*)d_in[0], (const float*)d_in[1], (const float*)d_in[2],
        (const float*)d_in[3], (float*)d_out);
}

// Round 10
// 152.192 us; speedup vs baseline: 1.1428x; 1.1428x over previous
//
#include <hip/hip_runtime.h>
#include <hip/hip_bf16.h>

// Round 10 = r9 structure with the register budget restored.
//  r9's regression was launch_bounds(512,6): VGPR capped at 40 -> prefetch
//  state couldn't stay in flight + spill (WRITE_SIZE 20.5K); and the hoped
//  occupancy gain was impossible (grid 512 = 2 blocks/CU hard cap).
//  This round: launch_bounds(512,4) (VGPR cap 128, r7's regime), keeping
//  r9's two LDS-pipe cuts:
//   1. PV via 8 ds_read_b128 (interleaved+XOR-swizzled V^T layout, each b128
//      feeds two chunk fragments)  [bank-audited volume-minimal]
//   2. mask from global dwordx4 (L1-hot quad-broadcast) folded into softmax
//      fma; no Em in LDS.
//  All math/layouts r9-identical (passed, absmax 1.95e-3).

typedef __attribute__((ext_vector_type(8))) short bf16x8;
typedef __attribute__((ext_vector_type(4))) short bf16x4;
typedef __attribute__((ext_vector_type(4))) float f32x4;

#define B_ 2
#define S_ 2048
#define H_ 16
#define D_ 64
#define BQ 128
#define BK 64
#define NT (S_ / BK)
#define LDK 72                 // padded LDS row (144 B)
#define ROWSZ (H_ * D_)        // 1024 floats between s rows

#define LOG2E  1.44269504088896340736f
#define SCALE2 (0.125f * LOG2E)

__device__ __forceinline__ unsigned pack2(float a, float b) {
    union { __hip_bfloat162 h; unsigned u; } x;
    x.h = __float22bfloat162_rn(make_float2(a, b));   // v_cvt_pk_bf16_f32
    return x.u;
}

__device__ __forceinline__ float fexp2(float x) {
#if __has_builtin(__builtin_amdgcn_exp2f)
    return __builtin_amdgcn_exp2f(x);
#else
    return __expf(x * 0.69314718055994531f);
#endif
}

__device__ __forceinline__ f32x4 mfma16(bf16x4 a, bf16x4 b, f32x4 c) {
#if __has_builtin(__builtin_amdgcn_mfma_f32_16x16x16bf16_1k)
    return __builtin_amdgcn_mfma_f32_16x16x16bf16_1k(a, b, c, 0, 0, 0);
#else
    bf16x8 a8 = {a[0], a[1], a[2], a[3], 0, 0, 0, 0};
    bf16x8 b8 = {b[0], b[1], b[2], b[3], 0, 0, 0, 0};
    return __builtin_amdgcn_mfma_f32_16x16x32_bf16(a8, b8, c, 0, 0, 0);
#endif
}

__global__ __launch_bounds__(512, 4)
void fattn_kernel(const float* __restrict__ qg,
                  const float* __restrict__ kg,
                  const float* __restrict__ vg,
                  const float* __restrict__ maskg,
                  float* __restrict__ outg)
{
    __shared__ __attribute__((aligned(16))) ushort Ks[2][BK * LDK];  // row=key, col=d
    __shared__ __attribute__((aligned(16))) ushort Vt[2][D_ * LDK];  // row=d, interleaved+swizzled

    const int qt = blockIdx.x, h = blockIdx.y, b = blockIdx.z;
    const int tid = threadIdx.x;
    const int w = tid >> 6, lane = tid & 63, g = lane >> 4, l15 = lane & 15;
    const int h3 = l15 >> 3;

    // ---- Q fragment (B-operand, x32), scale folded in ----
    const int qrow = qt * BQ + w * 16 + l15;
    const float* qp = qg + (size_t)(b * S_ + qrow) * ROWSZ + h * D_;
    bf16x8 qf[2];
#pragma unroll
    for (int half = 0; half < 2; ++half) {
        float4 f0 = *(const float4*)(qp + half * 32 + g * 8);
        float4 f1 = *(const float4*)(qp + half * 32 + g * 8 + 4);
        union { bf16x8 v; uint4 u; } x;
        x.u = make_uint4(pack2(f0.x * SCALE2, f0.y * SCALE2),
                         pack2(f0.z * SCALE2, f0.w * SCALE2),
                         pack2(f1.x * SCALE2, f1.y * SCALE2),
                         pack2(f1.z * SCALE2, f1.w * SCALE2));
        qf[half] = x.v;
    }

    // staging maps
    const int skey16 = tid >> 4;        // K rows (tid>>4), +32 second pass
    const int sd4    = (tid & 15) * 4;  // K d-offset (float4)
    const int svd    = lane;            // V: d = lane
    const int K0     = 32 * (w & 1) + 4 * (w >> 1);   // V key-remap base
    const int vphys  = (w ^ ((lane >> 3) & 7)) * 8;   // XOR-swizzled granule

    const size_t kvbase = (size_t)b * S_ * ROWSZ + h * D_;
    const float* maskb = maskg + (size_t)b * S_;

    float4 kpre0, kpre1;
    float  vpre[8];
    auto prefetch = [&](int kt) {
        const float* kb = kg + kvbase + (size_t)kt * BK * ROWSZ;
        kpre0 = *(const float4*)(kb + (size_t)skey16 * ROWSZ + sd4);
        kpre1 = *(const float4*)(kb + (size_t)(skey16 + 32) * ROWSZ + sd4);
        const float* vb = vg + kvbase + (size_t)kt * BK * ROWSZ + svd;
#pragma unroll
        for (int p = 0; p < 4; ++p) {
            vpre[p]     = vb[(size_t)(K0 + p) * ROWSZ];
            vpre[4 + p] = vb[(size_t)(K0 + 16 + p) * ROWSZ];
        }
    };
    auto stage = [&](int buf) {
        *(uint2*)&Ks[buf][skey16 * LDK + sd4] =
            make_uint2(pack2(kpre0.x, kpre0.y), pack2(kpre0.z, kpre0.w));
        *(uint2*)&Ks[buf][(skey16 + 32) * LDK + sd4] =
            make_uint2(pack2(kpre1.x, kpre1.y), pack2(kpre1.z, kpre1.w));
        *(uint4*)&Vt[buf][svd * LDK + vphys] =
            make_uint4(pack2(vpre[0], vpre[1]), pack2(vpre[2], vpre[3]),
                       pack2(vpre[4], vpre[5]), pack2(vpre[6], vpre[7]));
    };

    float l_r = 0.0f;                   // per-lane (q=l15) partial denominator
    f32x4 o_acc[4];
#pragma unroll
    for (int t = 0; t < 4; ++t) o_acc[t] = (f32x4){0.f, 0.f, 0.f, 0.f};

    prefetch(0);
    stage(0);
    __syncthreads();

    const int koff = l15 * LDK + g * 8;

    for (int kt = 0; kt < NT; ++kt) {
        const int cur = kt & 1;
        if (kt + 1 < NT) prefetch(kt + 1);   // loads in flight across compute

        // ---- St = K Q^T (C=0) : St[key=t*16+g*4+r][q=l15] ----
        const ushort* ks = Ks[cur];
        float sv[4][4];
#pragma unroll
        for (int t = 0; t < 4; ++t) {
            f32x4 acc = (f32x4){0.f, 0.f, 0.f, 0.f};
            bf16x8 kf0 = *(const bf16x8*)&ks[t * 16 * LDK + koff];
            bf16x8 kf1 = *(const bf16x8*)&ks[t * 16 * LDK + koff + 32];
            acc = __builtin_amdgcn_mfma_f32_16x16x32_bf16(kf0, qf[0], acc, 0, 0, 0);
            acc = __builtin_amdgcn_mfma_f32_16x16x32_bf16(kf1, qf[1], acc, 0, 0, 0);
            sv[t][0] = acc[0]; sv[t][1] = acc[1]; sv[t][2] = acc[2]; sv[t][3] = acc[3];
        }

        // ---- fixed-base softmax with mask from global (L1-hot broadcast) ----
        float rs = 0.f;
        bf16x4 pf[4];
#pragma unroll
        for (int t = 0; t < 4; ++t) {
            const f32x4 mk = *(const f32x4*)(maskb + kt * BK + t * 16 + g * 4);
            float p0 = fexp2(fmaf(mk[0], LOG2E, sv[t][0]));
            float p1 = fexp2(fmaf(mk[1], LOG2E, sv[t][1]));
            float p2 = fexp2(fmaf(mk[2], LOG2E, sv[t][2]));
            float p3 = fexp2(fmaf(mk[3], LOG2E, sv[t][3]));
            rs += (p0 + p1) + (p2 + p3);
            union { bf16x4 v; uint2 u; } x;
            x.u = make_uint2(pack2(p0, p1), pack2(p2, p3));
            pf[t] = x.v;
        }
        l_r += rs;

        // ---- O^T += V^T P^T : 8 b128 reads, each feeds 2 chunk fragments ----
        const ushort* vt = Vt[cur];
#pragma unroll
        for (int t2 = 0; t2 < 4; ++t2) {
            const int e = (2 * t2 + h3) & 7;          // (d>>3)&7 for d=t2*16+l15
            const int row = (t2 * 16 + l15) * LDK;
#pragma unroll
            for (int cc = 0; cc < 2; ++cc) {
                const int Gs = (2 * g + cc) ^ e;
                bf16x8 vv = *(const bf16x8*)&vt[row + Gs * 8];
                bf16x4 vlo = {vv[0], vv[1], vv[2], vv[3]};   // chunk 2cc
                bf16x4 vhi = {vv[4], vv[5], vv[6], vv[7]};   // chunk 2cc+1
                o_acc[t2] = mfma16(vlo, pf[2 * cc],     o_acc[t2]);
                o_acc[t2] = mfma16(vhi, pf[2 * cc + 1], o_acc[t2]);
            }
        }

        if (kt + 1 < NT) stage(cur ^ 1);    // vmcnt drain lands post-compute
        __syncthreads();                    // single barrier per tile
    }

    // ---- epilogue: reduce l across quads, normalize, store fp32 ----
    l_r += __shfl_xor(l_r, 16);
    l_r += __shfl_xor(l_r, 32);
    const float inv = 1.0f / l_r;
    float* op = outg + (size_t)(b * S_ + qrow) * ROWSZ + h * D_;
#pragma unroll
    for (int t2 = 0; t2 < 4; ++t2)
#pragma unroll
        for (int r = 0; r < 4; ++r)
            op[t2 * 16 + g * 4 + r] = o_acc[t2][r] * inv;
}

extern "C" void kernel_launch(void* const* d_in, const int* in_sizes, int n_in,
                              void* d_out, int out_size, void* d_ws, size_t ws_size,
                              hipStream_t stream) {
    dim3 grid(S_ / BQ, H_, B_);   // (16,16,2) = 512 blocks, 2/CU
    fattn_kernel<<<grid, dim3(512), 0, stream>>>(
        (const float*)d_in[0], (const float*)d_in[1], (const float*)d_in[2],
        (const float*)d_in[3], (float*)d_out);
}